// Round 7
// baseline (78.442 us; speedup 1.0000x reference)
//
#include <hip/hip_runtime.h>
#include <math.h>

typedef float v4 __attribute__((ext_vector_type(4)));

// Exact-stable softplus (setup / tail only)
__device__ __forceinline__ float spf(float x) {
    float a = fabsf(x);
    float e = __expf(-a);
    float l = __logf(1.0f + e);
    return fmaxf(x, 0.0f) + l;
}
__device__ __forceinline__ float sigm(float x) {
    return 1.0f / (1.0f + __expf(-x));
}
// Naive softplus: fine for z in (-80, 80); used where range is known safe.
__device__ __forceinline__ float spn(float x) {
    return __logf(1.0f + __expf(x));
}
// Overflow-guarded naive softplus: identity for z>30 (err < 1e-13), else naive.
__device__ __forceinline__ float sps(float x) {
    float v = __logf(1.0f + __expf(x));
    return x > 30.0f ? x : v;
}
__device__ __forceinline__ v4 splat(float s) { v4 r; r.x=s; r.y=s; r.z=s; r.w=s; return r; }
__device__ __forceinline__ v4 sp4n(v4 x) { v4 r; r.x=spn(x.x); r.y=spn(x.y); r.z=spn(x.z); r.w=spn(x.w); return r; }
__device__ __forceinline__ v4 sp4s(v4 x) { v4 r; r.x=sps(x.x); r.y=sps(x.y); r.z=sps(x.z); r.w=sps(x.w); return r; }
__device__ __forceinline__ v4 vfma(v4 a, float b, v4 c) {
    return __builtin_elementwise_fma(a, splat(b), c);
}
__device__ __forceinline__ v4 vmin(v4 a, v4 b) {
    v4 r; r.x=fminf(a.x,b.x); r.y=fminf(a.y,b.y); r.z=fminf(a.z,b.z); r.w=fminf(a.w,b.w); return r;
}

// Setup (1 thread): e_id, h_s, collapse-validity flag, collapsed affine (w_c, b_c).
// ws layout: [0]=e_id [1]=h_s [2]=ok [3..7]=w_c [8]=b_c
__global__ void setup_kernel(const float* __restrict__ W0, const float* __restrict__ b0,
                             const float* __restrict__ Wh, const float* __restrict__ bh,
                             const float* __restrict__ Wf, const float* __restrict__ bf,
                             float* __restrict__ ws) {
    if (threadIdx.x != 0 || blockIdx.x != 0) return;
    // ---- exact forward at identity ----
    float x[4] = {3.f, 1.f, -1.f, 3.f};
    float zin[5], h[5], zh[4][5];
    for (int j = 0; j < 5; ++j) {
        float z = b0[j];
        for (int m = 0; m < 4; ++m) z += x[m] * W0[m * 5 + j];
        zin[j] = z; h[j] = spf(z);
    }
    for (int i = 0; i < 4; ++i) {
        float hn[5];
        for (int j = 0; j < 5; ++j) {
            float z = bh[i * 5 + j];
            for (int k = 0; k < 5; ++k) z += h[k] * Wh[i * 25 + k * 5 + j];
            zh[i][j] = z; hn[j] = spf(z);
        }
        for (int j = 0; j < 5; ++j) h[j] = hn[j];
    }
    float zf = bf[0];
    for (int k = 0; k < 5; ++k) zf += h[k] * Wf[k];
    float e_id = spf(zf);
    // ---- backprop to invariants ----
    float d[5];
    float szf = sigm(zf);
    for (int k = 0; k < 5; ++k) d[k] = Wf[k] * szf;
    for (int i = 3; i >= 0; --i) {
        float dz[5];
        for (int j = 0; j < 5; ++j) dz[j] = d[j] * sigm(zh[i][j]);
        for (int k = 0; k < 5; ++k) {
            float acc = 0.f;
            for (int j = 0; j < 5; ++j) acc += Wh[i * 25 + k * 5 + j] * dz[j];
            d[k] = acc;
        }
    }
    float dz0[5], g[4];
    for (int j = 0; j < 5; ++j) dz0[j] = d[j] * sigm(zin[j]);
    for (int m = 0; m < 4; ++m) {
        float acc = 0.f;
        for (int j = 0; j < 5; ++j) acc += W0[m * 5 + j] * dz0[j];
        g[m] = acc;
    }
    ws[0] = e_id;
    ws[1] = -(2.f * g[0] + g[1] - g[2] + 4.f * g[3]);

    // ---- collapsed affine for hidden layers 2,3 + final (identity-activation regime) ----
    const float T = 9.0f;
    const float* W2 = Wh + 2 * 25; const float* B2 = bh + 2 * 5;
    const float* W3 = Wh + 3 * 25; const float* B3 = bh + 3 * 5;
    // u3 = W3 * Wf ; bacc = bf + B3.Wf
    float u3[5], bacc = bf[0];
    for (int k = 0; k < 5; ++k) {
        float a = 0.f;
        for (int j = 0; j < 5; ++j) a += W3[k * 5 + j] * Wf[j];
        u3[k] = a;
    }
    for (int j = 0; j < 5; ++j) bacc += B3[j] * Wf[j];
    // w_c = W2 * u3 ; bacc += B2.u3
    float wc[5];
    for (int k = 0; k < 5; ++k) {
        float a = 0.f;
        for (int j = 0; j < 5; ++j) a += W2[k * 5 + j] * u3[j];
        wc[k] = a;
    }
    for (int j = 0; j < 5; ++j) bacc += B2[j] * u3[j];
    // validity: nonneg weights + z>=T propagates through l=2, l=3, final
    bool ok = true;
    for (int i = 0; i < 25; ++i) { if (W2[i] < 0.f || W3[i] < 0.f) ok = false; }
    for (int j = 0; j < 5; ++j)  { if (Wf[j] < 0.f) ok = false; }
    for (int j = 0; j < 5; ++j) {
        float cs2 = 0.f, cs3 = 0.f;
        for (int k = 0; k < 5; ++k) { cs2 += W2[k * 5 + j]; cs3 += W3[k * 5 + j]; }
        if (T * cs2 + B2[j] < T) ok = false;
        if (T * cs3 + B3[j] < T) ok = false;
    }
    {
        float sf = 0.f;
        for (int j = 0; j < 5; ++j) sf += Wf[j];
        if (T * sf + bf[0] < T) ok = false;
    }
    ws[2] = ok ? 1.0f : 0.0f;
    for (int k = 0; k < 5; ++k) ws[3 + k] = wc[k];
    ws[8] = bacc;
}

__device__ __forceinline__ float scalar_sample(const float* f,
        const float* W0, const float* b0, const float* Wh, const float* bh,
        const float* Wf, const float* bf, float e_id, float h_s) {
    float f0=f[0],f1=f[1],f2=f[2],f3=f[3],f4=f[4],f5=f[5],f6=f[6],f7=f[7],f8=f[8];
    float c00=f0*f0+f3*f3+f6*f6, c11=f1*f1+f4*f4+f7*f7, c22=f2*f2+f5*f5+f8*f8;
    float c01=f0*f1+f3*f4+f6*f7, c02=f0*f2+f3*f5+f6*f8, c12=f1*f2+f4*f5+f7*f8;
    float trC=c00+c11+c22;
    float trC2=c00*c00+c11*c11+c22*c22+2.f*(c01*c01+c02*c02+c12*c12);
    float I2=0.5f*(trC*trC-trC2);
    float J=f0*(f4*f8-f5*f7)-f1*(f3*f8-f5*f6)+f2*(f3*f7-f4*f6);
    float h[5];
    for (int j=0;j<5;++j)
        h[j]=spf(b0[j]+trC*W0[j]+J*(W0[5+j]-W0[10+j])+I2*W0[15+j]);
    for (int l=0;l<4;++l){
        float hn[5];
        for (int j=0;j<5;++j){
            float z=bh[l*5+j];
            for (int k=0;k<5;++k) z=fmaf(h[k],Wh[l*25+k*5+j],z);
            hn[j]=spf(z);
        }
        for (int j=0;j<5;++j) h[j]=hn[j];
    }
    float zf=bf[0];
    for (int k=0;k<5;++k) zf=fmaf(h[k],Wf[k],zf);
    return (spf(zf)-e_id)+h_s*0.5f*(trC-3.0f);
}

__device__ __forceinline__ void inv9(
        float f0, float f1, float f2, float f3, float f4,
        float f5, float f6, float f7, float f8,
        float& tc_o, float& J_o, float& I2_o) {
    float c00=f0*f0+f3*f3+f6*f6, c11=f1*f1+f4*f4+f7*f7, c22=f2*f2+f5*f5+f8*f8;
    float c01=f0*f1+f3*f4+f6*f7, c02=f0*f2+f3*f5+f6*f8, c12=f1*f2+f4*f5+f7*f8;
    float tc=c00+c11+c22;
    float trC2=c00*c00+c11*c11+c22*c22+2.f*(c01*c01+c02*c02+c12*c12);
    tc_o=tc;
    I2_o=0.5f*(tc*tc-trC2);
    J_o=f0*(f4*f8-f5*f7)-f1*(f3*f8-f5*f6)+f2*(f3*f7-f4*f6);
}

// Thread t -> samples [4t,4t+4). Compute through hidden-layer-2 pre-activation;
// if wave-uniformly min(z) > 9 (and setup validated propagation), layers 2,3 +
// final collapse to a precomputed affine (softplus==identity there to ~1e-4,
// amplified <= ~3e-3 << 0.985 tolerance).
__global__ __launch_bounds__(256, 8) void main_kernel(
        const float* __restrict__ F,
        const float* __restrict__ W0, const float* __restrict__ b0,
        const float* __restrict__ Wh, const float* __restrict__ bh,
        const float* __restrict__ Wf, const float* __restrict__ bf,
        const float* __restrict__ cs,   // [e_id,h_s,ok,wc0..4,bc]
        float* __restrict__ out, int n) {
    const long long t = (long long)blockIdx.x * blockDim.x + threadIdx.x;
    const long long i0 = t * 4;
    if (i0 >= n) return;
    const float eid = cs[0], hs = cs[1];

    if (i0 + 4 <= (long long)n) {
        const v4* p = (const v4*)(F + i0 * 9);
        v4 a0=p[0],a1=p[1],a2=p[2],a3=p[3],a4=p[4],a5=p[5],a6=p[6],a7=p[7],a8=p[8];

        float tc0,j0,q0, tc1,j1,q1, tc2,j2,q2, tc3,j3,q3;
        inv9(a0.x,a0.y,a0.z,a0.w, a1.x,a1.y,a1.z,a1.w, a2.x, tc0,j0,q0);
        inv9(a2.y,a2.z,a2.w, a3.x,a3.y,a3.z,a3.w, a4.x,a4.y, tc1,j1,q1);
        inv9(a4.z,a4.w, a5.x,a5.y,a5.z,a5.w, a6.x,a6.y,a6.z, tc2,j2,q2);
        inv9(a6.w, a7.x,a7.y,a7.z,a7.w, a8.x,a8.y,a8.z,a8.w, tc3,j3,q3);
        v4 trC, J, I2;
        trC.x=tc0; trC.y=tc1; trC.z=tc2; trC.w=tc3;
        J.x=j0; J.y=j1; J.z=j2; J.w=j3;
        I2.x=q0; I2.y=q1; I2.z=q2; I2.w=q3;

        // layer 0 (input layer, fold J/-J rows); z bounded moderate -> naive softplus safe
        v4 h0,h1,h2,h3,h4;
        {
            v4 z;
            #define L0(J_, H_) \
                z = splat(b0[J_]); \
                z = vfma(trC, W0[J_], z); \
                z = vfma(J, W0[5+J_]-W0[10+J_], z); \
                z = vfma(I2, W0[15+J_], z); \
                H_ = sp4n(z);
            L0(0,h0) L0(1,h1) L0(2,h2) L0(3,h3) L0(4,h4)
            #undef L0
        }
        {
            #define ZJ(L_, J_, Z_) \
                Z_ = splat(bh[(L_)*5+J_]); \
                Z_ = vfma(h0, Wh[(L_)*25+0*5+J_], Z_); \
                Z_ = vfma(h1, Wh[(L_)*25+1*5+J_], Z_); \
                Z_ = vfma(h2, Wh[(L_)*25+2*5+J_], Z_); \
                Z_ = vfma(h3, Wh[(L_)*25+3*5+J_], Z_); \
                Z_ = vfma(h4, Wh[(L_)*25+4*5+J_], Z_);

            // hidden layer 1 (Wh[0]): guarded softplus
            v4 z0,z1,z2,z3,z4;
            ZJ(0,0,z0) ZJ(0,1,z1) ZJ(0,2,z2) ZJ(0,3,z3) ZJ(0,4,z4)
            h0=sp4s(z0); h1=sp4s(z1); h2=sp4s(z2); h3=sp4s(z3); h4=sp4s(z4);

            // hidden layer 2 (Wh[1]) pre-activation
            v4 w0,w1,w2,w3,w4;
            ZJ(1,0,w0) ZJ(1,1,w1) ZJ(1,2,w2) ZJ(1,3,w3) ZJ(1,4,w4)

            v4 m = vmin(vmin(vmin(w0,w1),vmin(w2,w3)),w4);
            float mm = fminf(fminf(m.x,m.y),fminf(m.z,m.w));
            v4 e;
            if (cs[2] != 0.0f && __all(mm > 9.0f)) {
                // collapsed: softplus==identity for layers 2,3 and final
                v4 zf = splat(cs[8]);
                zf = vfma(w0, cs[3], zf);
                zf = vfma(w1, cs[4], zf);
                zf = vfma(w2, cs[5], zf);
                zf = vfma(w3, cs[6], zf);
                zf = vfma(w4, cs[7], zf);
                e = zf;
            } else {
                // exact path
                h0=sp4s(w0); h1=sp4s(w1); h2=sp4s(w2); h3=sp4s(w3); h4=sp4s(w4);
                #pragma unroll
                for (int l = 2; l < 4; ++l) {
                    v4 y0,y1,y2,y3,y4;
                    ZJ(l,0,y0) ZJ(l,1,y1) ZJ(l,2,y2) ZJ(l,3,y3) ZJ(l,4,y4)
                    h0=sp4s(y0); h1=sp4s(y1); h2=sp4s(y2); h3=sp4s(y3); h4=sp4s(y4);
                }
                v4 zf = splat(bf[0]);
                zf = vfma(h0, Wf[0], zf);
                zf = vfma(h1, Wf[1], zf);
                zf = vfma(h2, Wf[2], zf);
                zf = vfma(h3, Wf[3], zf);
                zf = vfma(h4, Wf[4], zf);
                e = sp4s(zf);
            }
            #undef ZJ

            v4 res = (e - splat(eid)) + splat(hs * 0.5f) * (trC - splat(3.0f));
            *(v4*)(out + i0) = res;
        }
    } else {
        for (int s = 0; s < (int)(n - i0); ++s)
            out[i0 + s] = scalar_sample(F + (size_t)(i0 + s) * 9, W0, b0, Wh, bh, Wf, bf, eid, hs);
    }
}

extern "C" void kernel_launch(void* const* d_in, const int* in_sizes, int n_in,
                              void* d_out, int out_size, void* d_ws, size_t ws_size,
                              hipStream_t stream) {
    const float* F  = (const float*)d_in[0];
    const float* W0 = (const float*)d_in[1];
    const float* b0 = (const float*)d_in[2];
    const float* Wh = (const float*)d_in[3];
    const float* bh = (const float*)d_in[4];
    const float* Wf = (const float*)d_in[5];
    const float* bf = (const float*)d_in[6];
    float* out = (float*)d_out;
    float* ws  = (float*)d_ws;
    int n = in_sizes[0] / 9;
    setup_kernel<<<1, 64, 0, stream>>>(W0, b0, Wh, bh, Wf, bf, ws);
    int block = 256;
    long long threads = ((long long)n + 3) / 4;
    int grid = (int)((threads + block - 1) / block);
    if (grid < 1) grid = 1;
    main_kernel<<<grid, block, 0, stream>>>(F, W0, b0, Wh, bh, Wf, bf, ws, out, n);
}

// Round 8
// 51.937 us; speedup vs baseline: 1.5103x; 1.5103x over previous
//
#include <hip/hip_runtime.h>
#include <math.h>

typedef float v4 __attribute__((ext_vector_type(4)));

// Full stable softplus: log(1+e^x) = max(x,0) + log(1 + e^-|x|)   [7 inst, 2 trans]
__device__ __forceinline__ float spf(float x) {
    float a = fabsf(x);
    float e = __expf(-a);
    float l = __logf(1.0f + e);
    return fmaxf(x, 0.0f) + l;
}
__device__ __forceinline__ float sigm(float x) {
    return 1.0f / (1.0f + __expf(-x));
}
__device__ __forceinline__ v4 splat(float s) { v4 r; r.x=s; r.y=s; r.z=s; r.w=s; return r; }
__device__ __forceinline__ v4 sp4(v4 x) {
    v4 r; r.x=spf(x.x); r.y=spf(x.y); r.z=spf(x.z); r.w=spf(x.w); return r;
}
// Quick softplus for z > 2: softplus(z) = z + log1p(e^-z) ~= z + e^-z, |err| <= 0.0084  [3 inst, 1 trans]
__device__ __forceinline__ v4 spq4(v4 x) {
    v4 r;
    r.x = x.x + __expf(-x.x);
    r.y = x.y + __expf(-x.y);
    r.z = x.z + __expf(-x.z);
    r.w = x.w + __expf(-x.w);
    return r;
}
__device__ __forceinline__ v4 vfma(v4 a, float b, v4 c) {
    return __builtin_elementwise_fma(a, splat(b), c);
}
__device__ __forceinline__ v4 vmin(v4 a, v4 b) {
    v4 r; r.x=fminf(a.x,b.x); r.y=fminf(a.y,b.y); r.z=fminf(a.z,b.z); r.w=fminf(a.w,b.w); return r;
}

// Single-thread kernel: energy at identity + scalar h_s with H = h_s * I.
// At F=I: x = [trC,J,-J,I2] = [3,1,-1,3]; dX/dF = [2I, I, -I, 4I] (exact zeros off-diag).
__global__ void setup_kernel(const float* __restrict__ W0, const float* __restrict__ b0,
                             const float* __restrict__ Wh, const float* __restrict__ bh,
                             const float* __restrict__ Wf, const float* __restrict__ bf,
                             float* __restrict__ ws) {
    if (threadIdx.x != 0 || blockIdx.x != 0) return;
    float x[4] = {3.f, 1.f, -1.f, 3.f};
    float zin[5], h[5], zh[4][5];
    for (int j = 0; j < 5; ++j) {
        float z = b0[j];
        for (int m = 0; m < 4; ++m) z += x[m] * W0[m * 5 + j];
        zin[j] = z; h[j] = spf(z);
    }
    for (int i = 0; i < 4; ++i) {
        float hn[5];
        for (int j = 0; j < 5; ++j) {
            float z = bh[i * 5 + j];
            for (int k = 0; k < 5; ++k) z += h[k] * Wh[i * 25 + k * 5 + j];
            zh[i][j] = z; hn[j] = spf(z);
        }
        for (int j = 0; j < 5; ++j) h[j] = hn[j];
    }
    float zf = bf[0];
    for (int k = 0; k < 5; ++k) zf += h[k] * Wf[k];
    float e_id = spf(zf);
    float d[5];
    float szf = sigm(zf);
    for (int k = 0; k < 5; ++k) d[k] = Wf[k] * szf;
    for (int i = 3; i >= 0; --i) {
        float dz[5];
        for (int j = 0; j < 5; ++j) dz[j] = d[j] * sigm(zh[i][j]);
        for (int k = 0; k < 5; ++k) {
            float acc = 0.f;
            for (int j = 0; j < 5; ++j) acc += Wh[i * 25 + k * 5 + j] * dz[j];
            d[k] = acc;
        }
    }
    float dz0[5], g[4];
    for (int j = 0; j < 5; ++j) dz0[j] = d[j] * sigm(zin[j]);
    for (int m = 0; m < 4; ++m) {
        float acc = 0.f;
        for (int j = 0; j < 5; ++j) acc += W0[m * 5 + j] * dz0[j];
        g[m] = acc;
    }
    float h_s = -(2.f * g[0] + g[1] - g[2] + 4.f * g[3]);
    ws[0] = e_id;
    ws[1] = h_s;
}

__device__ __forceinline__ float scalar_sample(const float* f,
        const float* W0, const float* b0, const float* Wh, const float* bh,
        const float* Wf, const float* bf, float e_id, float h_s) {
    float f0=f[0],f1=f[1],f2=f[2],f3=f[3],f4=f[4],f5=f[5],f6=f[6],f7=f[7],f8=f[8];
    float c00=f0*f0+f3*f3+f6*f6, c11=f1*f1+f4*f4+f7*f7, c22=f2*f2+f5*f5+f8*f8;
    float c01=f0*f1+f3*f4+f6*f7, c02=f0*f2+f3*f5+f6*f8, c12=f1*f2+f4*f5+f7*f8;
    float trC=c00+c11+c22;
    float trC2=c00*c00+c11*c11+c22*c22+2.f*(c01*c01+c02*c02+c12*c12);
    float I2=0.5f*(trC*trC-trC2);
    float J=f0*(f4*f8-f5*f7)-f1*(f3*f8-f5*f6)+f2*(f3*f7-f4*f6);
    float h[5];
    for (int j=0;j<5;++j)
        h[j]=spf(b0[j]+trC*W0[j]+J*(W0[5+j]-W0[10+j])+I2*W0[15+j]);
    for (int l=0;l<4;++l){
        float hn[5];
        for (int j=0;j<5;++j){
            float z=bh[l*5+j];
            for (int k=0;k<5;++k) z=fmaf(h[k],Wh[l*25+k*5+j],z);
            hn[j]=spf(z);
        }
        for (int j=0;j<5;++j) h[j]=hn[j];
    }
    float zf=bf[0];
    for (int k=0;k<5;++k) zf=fmaf(h[k],Wf[k],zf);
    return (spf(zf)-e_id)+h_s*0.5f*(trC-3.0f);
}

// Invariants from 9 named scalars (all register-resident, no local arrays).
__device__ __forceinline__ void inv9(
        float f0, float f1, float f2, float f3, float f4,
        float f5, float f6, float f7, float f8,
        float& tc_o, float& J_o, float& I2_o) {
    float c00=f0*f0+f3*f3+f6*f6, c11=f1*f1+f4*f4+f7*f7, c22=f2*f2+f5*f5+f8*f8;
    float c01=f0*f1+f3*f4+f6*f7, c02=f0*f2+f3*f5+f6*f8, c12=f1*f2+f4*f5+f7*f8;
    float tc=c00+c11+c22;
    float trC2=c00*c00+c11*c11+c22*c22+2.f*(c01*c01+c02*c02+c12*c12);
    tc_o=tc;
    I2_o=0.5f*(tc*tc-trC2);
    J_o=f0*(f4*f8-f5*f7)-f1*(f3*f8-f5*f6)+f2*(f3*f7-f4*f6);
}

// One-shot: thread t -> samples [4t, 4t+4). Cascaded softplus per hidden layer:
//   wave-uniform min>17 -> identity (exact in fp32)
//   wave-uniform min>2  -> z + exp(-z)  (|err|<=0.0084, amplified << tolerance)
//   else                -> full stable softplus
__global__ __launch_bounds__(256, 8) void main_kernel(
        const float* __restrict__ F,
        const float* __restrict__ W0, const float* __restrict__ b0,
        const float* __restrict__ Wh, const float* __restrict__ bh,
        const float* __restrict__ Wf, const float* __restrict__ bf,
        const float* __restrict__ cs,   // [e_id, h_s]
        float* __restrict__ out, int n) {
    const long long t = (long long)blockIdx.x * blockDim.x + threadIdx.x;
    const long long i0 = t * 4;
    if (i0 >= n) return;
    const float eid = cs[0], hs = cs[1];

    if (i0 + 4 <= (long long)n) {
        const v4* p = (const v4*)(F + i0 * 9);
        v4 a0=p[0],a1=p[1],a2=p[2],a3=p[3],a4=p[4],a5=p[5],a6=p[6],a7=p[7],a8=p[8];

        // transpose via named extracts (pure renames)
        float tc0,j0,q0, tc1,j1,q1, tc2,j2,q2, tc3,j3,q3;
        inv9(a0.x,a0.y,a0.z,a0.w, a1.x,a1.y,a1.z,a1.w, a2.x, tc0,j0,q0);
        inv9(a2.y,a2.z,a2.w, a3.x,a3.y,a3.z,a3.w, a4.x,a4.y, tc1,j1,q1);
        inv9(a4.z,a4.w, a5.x,a5.y,a5.z,a5.w, a6.x,a6.y,a6.z, tc2,j2,q2);
        inv9(a6.w, a7.x,a7.y,a7.z,a7.w, a8.x,a8.y,a8.z,a8.w, tc3,j3,q3);
        v4 trC, J, I2;
        trC.x=tc0; trC.y=tc1; trC.z=tc2; trC.w=tc3;
        J.x=j0; J.y=j1; J.z=j2; J.w=j3;
        I2.x=q0; I2.y=q1; I2.z=q2; I2.w=q3;

        // input layer (fold J and -J rows): z can be near/below 0 -> full softplus
        v4 h0,h1,h2,h3,h4;
        {
            v4 z;
            #define L0(J_, H_) \
                z = splat(b0[J_]); \
                z = vfma(trC, W0[J_], z); \
                z = vfma(J, W0[5+J_]-W0[10+J_], z); \
                z = vfma(I2, W0[15+J_], z); \
                H_ = sp4(z);
            L0(0,h0) L0(1,h1) L0(2,h2) L0(3,h3) L0(4,h4)
            #undef L0
        }
        // hidden layers 1..4 with cascaded activation
        #pragma unroll
        for (int l = 0; l < 4; ++l) {
            v4 z0,z1,z2,z3,z4;
            #define ZJ(J_, Z_) \
                Z_ = splat(bh[l*5+J_]); \
                Z_ = vfma(h0, Wh[l*25+0*5+J_], Z_); \
                Z_ = vfma(h1, Wh[l*25+1*5+J_], Z_); \
                Z_ = vfma(h2, Wh[l*25+2*5+J_], Z_); \
                Z_ = vfma(h3, Wh[l*25+3*5+J_], Z_); \
                Z_ = vfma(h4, Wh[l*25+4*5+J_], Z_);
            ZJ(0,z0) ZJ(1,z1) ZJ(2,z2) ZJ(3,z3) ZJ(4,z4)
            #undef ZJ
            v4 m = vmin(vmin(vmin(z0,z1),vmin(z2,z3)),z4);
            float mm = fminf(fminf(m.x,m.y),fminf(m.z,m.w));
            if (__all(mm > 17.0f)) {
                h0=z0; h1=z1; h2=z2; h3=z3; h4=z4;          // identity, exact
            } else if (__all(mm > 2.0f)) {
                h0=spq4(z0); h1=spq4(z1); h2=spq4(z2); h3=spq4(z3); h4=spq4(z4);
            } else {
                h0=sp4(z0); h1=sp4(z1); h2=sp4(z2); h3=sp4(z3); h4=sp4(z4);
            }
        }
        v4 zf = splat(bf[0]);
        zf = vfma(h0, Wf[0], zf);
        zf = vfma(h1, Wf[1], zf);
        zf = vfma(h2, Wf[2], zf);
        zf = vfma(h3, Wf[3], zf);
        zf = vfma(h4, Wf[4], zf);
        float mf = fminf(fminf(zf.x, zf.y), fminf(zf.z, zf.w));
        v4 e;
        if (__all(mf > 17.0f)) e = zf;
        else if (__all(mf > 2.0f)) e = spq4(zf);
        else e = sp4(zf);

        v4 res = (e - splat(eid)) + splat(hs * 0.5f) * (trC - splat(3.0f));
        *(v4*)(out + i0) = res;
    } else {
        for (int s = 0; s < (int)(n - i0); ++s)
            out[i0 + s] = scalar_sample(F + (size_t)(i0 + s) * 9, W0, b0, Wh, bh, Wf, bf, eid, hs);
    }
}

extern "C" void kernel_launch(void* const* d_in, const int* in_sizes, int n_in,
                              void* d_out, int out_size, void* d_ws, size_t ws_size,
                              hipStream_t stream) {
    const float* F  = (const float*)d_in[0];
    const float* W0 = (const float*)d_in[1];
    const float* b0 = (const float*)d_in[2];
    const float* Wh = (const float*)d_in[3];
    const float* bh = (const float*)d_in[4];
    const float* Wf = (const float*)d_in[5];
    const float* bf = (const float*)d_in[6];
    float* out = (float*)d_out;
    float* ws  = (float*)d_ws;
    int n = in_sizes[0] / 9;
    setup_kernel<<<1, 64, 0, stream>>>(W0, b0, Wh, bh, Wf, bf, ws);
    int block = 256;
    long long threads = ((long long)n + 3) / 4;
    int grid = (int)((threads + block - 1) / block);
    if (grid < 1) grid = 1;
    main_kernel<<<grid, block, 0, stream>>>(F, W0, b0, Wh, bh, Wf, bf, ws, out, n);
}